// Round 6
// baseline (208.198 us; speedup 1.0000x reference)
//
#include <hip/hip_runtime.h>
#include <hip/hip_bf16.h>
#include <math.h>
#include <stdint.h>

typedef __attribute__((ext_vector_type(8))) short short8;
typedef __attribute__((ext_vector_type(4))) float f32x4;

__device__ inline short f2bf(float x) {
  union { float f; uint32_t u; } c; c.f = x;
  uint32_t r = (c.u + 0x7FFFu + ((c.u >> 16) & 1u)) >> 16;
  return (short)(uint16_t)r;
}
__device__ inline float bf2f(short s) {
  union { uint32_t u; float f; } c; c.u = ((uint32_t)(uint16_t)s) << 16;
  return c.f;
}

__device__ inline void gload16(const short* src, const char* ldsdst) {
  __builtin_amdgcn_global_load_lds(
      (const __attribute__((address_space(1))) void*)src,
      (__attribute__((address_space(3))) void*)ldsdst, 16, 0, 0);
}

#define BAR __builtin_amdgcn_s_barrier()
#define VMC(n) asm volatile("s_waitcnt vmcnt(" #n ")" ::: "memory")

// ---------------- prep: f32 -> bf16 for X and Kp in one launch ----------------
__global__ void cvt2_kernel(const float* __restrict__ X, const float* __restrict__ Kp,
                            short* __restrict__ Xb, short* __restrict__ Kb,
                            int n8x, int n8tot) {
  int i = blockIdx.x * blockDim.x + threadIdx.x;
  if (i >= n8tot) return;
  const float* src = (i < n8x) ? X + (size_t)i * 8 : Kp + (size_t)(i - n8x) * 8;
  short* dst = (i < n8x) ? Xb + (size_t)i * 8 : Kb + (size_t)(i - n8x) * 8;
  const float4* p = (const float4*)src;
  float4 a = p[0], b = p[1];
  short8 o;
  o[0] = f2bf(a.x); o[1] = f2bf(a.y); o[2] = f2bf(a.z); o[3] = f2bf(a.w);
  o[4] = f2bf(b.x); o[5] = f2bf(b.y); o[6] = f2bf(b.z); o[7] = f2bf(b.w);
  *(short8*)dst = o;
}

// ---------------- prep: V[4096,1024] f32 -> Vt[1024,4096] bf16 ----------------
__global__ void transpose_bf16_kernel(const float* __restrict__ V,
                                      short* __restrict__ Vt,
                                      int rows, int cols) {
  __shared__ float tile[64][65];
  int n0 = blockIdx.x * 64;
  int d0 = blockIdx.y * 64;
  int t = threadIdx.x;
#pragma unroll
  for (int r = 0; r < 16; ++r) {
    int idx = t + 256 * r;
    int rr = idx >> 6, cc = idx & 63;
    tile[rr][cc] = V[(size_t)(n0 + rr) * cols + d0 + cc];
  }
  __syncthreads();
#pragma unroll
  for (int r = 0; r < 16; ++r) {
    int idx = t + 256 * r;
    int dd = idx >> 6, nn = idx & 63;
    Vt[(size_t)(d0 + dd) * rows + n0 + nn] = f2bf(tile[nn][dd]);
  }
}

// ======== unified ring GEMM: C[8192,N] = A[8192,K] x B[N,K]^T ========
// BM=256, BK=32, 8 waves (WM x WN), 3-buffer LDS ring, stage 2 tiles ahead,
// 1 barrier + 1 counted vmcnt per K-tile (VMC always immediately before BAR).
template <int N, int K, int BN, int WM, int WN, bool SCORE>
__global__ __launch_bounds__(512, 2) void gemm_ring(
    const short* __restrict__ A, const short* __restrict__ Bm,
    void* __restrict__ Cout, float* __restrict__ rowss) {
  constexpr int NT = K / 32;
  static_assert(NT % 3 == 2, "tail assumes NT%3==2");
  constexpr int ASZ = 256 * 32 * 2;  // 16 KiB
  constexpr int BSZ = BN * 32 * 2;   // 16 or 8 KiB
  constexpr int SLOT = ASZ + BSZ;
  constexpr int BR = BN / 128;       // B rounds per tile (2 or 1)
  constexpr int LQ = 2 + BR;         // loads per tile (4 or 3)
  constexpr int MH2 = 256 / WM / 32; // m-frags per 128-row half (4 or 2)
  constexpr int RW = 128 / WM;       // rows per wave within a half
  constexpr int NTN = N / BN;

  __shared__ char lds[3 * SLOT];

  const int t = threadIdx.x, lane = t & 63, w = t >> 6;
  const int wm = w / WN, wn = w % WN;
  const int idx = lane & 15, g = lane >> 4;

  // XCD-aware bijective swizzle; grid = 32*NTN (multiple of 8)
  const int bid = blockIdx.x;
  const int id2 = (bid & 7) * (4 * NTN) + (bid >> 3);
  const int row0 = (id2 / NTN) * 256, col0 = (id2 % NTN) * BN;

  // staging: linear LDS dest t*16; source pre-swizzled so that LDS slot s_mem
  // of row r holds logical k-slot (s_mem ^ (r&3)).  round = 128 rows x 64 B.
  const int sxor = ((t & 3) ^ ((t >> 2) & 3)) * 8;
  const short* gAp = A + (size_t)(row0 + (t >> 2)) * K + sxor;
  const short* gBp = Bm + (size_t)(col0 + (t >> 2)) * K + sxor;

  auto STG = [&](int s, int T) {
    const int kt = T * 32;
    char* base = (char*)lds + s * SLOT + t * 16;
#pragma unroll
    for (int r = 0; r < 2; ++r)
      gload16(gAp + (size_t)(r * 128) * K + kt, base + r * 8192);
#pragma unroll
    for (int r = 0; r < BR; ++r)
      gload16(gBp + (size_t)(r * 128) * K + kt, base + ASZ + r * 8192);
  };

  // swizzled reads: want k-slot g of row r -> read slot g ^ (r&3); r&3 == idx&3
  const int rdx = ((g ^ (idx & 3)) << 4);
  short8 a[2][MH2], b4[4];
  auto LD = [&](int s) {
    const char* base = (char*)lds + s * SLOT;
#pragma unroll
    for (int nf = 0; nf < 4; ++nf) {
      const int col = (BN == 256) ? (wn * 32 + (nf & 1) * 16 + (nf >> 1) * 128)
                                  : (wn * 64 + nf * 16);
      b4[nf] = *(const short8*)(base + ASZ + (col + idx) * 64 + rdx);
    }
#pragma unroll
    for (int mh = 0; mh < 2; ++mh)
#pragma unroll
      for (int f = 0; f < MH2; ++f) {
        const int row = mh * 128 + wm * RW + f * 16 + idx;
        a[mh][f] = *(const short8*)(base + row * 64 + rdx);
      }
  };

  f32x4 acc[2 * MH2][4] = {};
  auto MFM = [&]() {
    __builtin_amdgcn_s_setprio(1);
#pragma unroll
    for (int mh = 0; mh < 2; ++mh)
#pragma unroll
      for (int f = 0; f < MH2; ++f)
#pragma unroll
        for (int nf = 0; nf < 4; ++nf)
          acc[mh * MH2 + f][nf] = __builtin_amdgcn_mfma_f32_16x16x32_bf16(
              a[mh][f], b4[nf], acc[mh * MH2 + f][nf], 0, 0, 0);
    __builtin_amdgcn_s_setprio(0);
  };

  auto ITER = [&](int T, int s, int s2, bool mainL) {
    if (mainL) STG(s2, T + 2);  // issue prefetch first (earliest HBM start)
    LD(s);
    MFM();
    if (mainL) {
      if constexpr (LQ == 4) { VMC(4); } else { VMC(3); }  // certify tile T+1
      BAR;
    } else if (T + 1 < NT) {
      VMC(0);  // tail: drain last tile's loads
      BAR;
    }
  };

  // prologue: stage tiles 0,1; certify tile 0 (tile 1 left in flight)
  STG(0, 0);
  STG(1, 1);
  if constexpr (LQ == 4) { VMC(4); } else { VMC(3); }
  BAR;

  for (int c = 0; c + 3 <= NT; c += 3) {
    ITER(c, 0, 2, true);
    ITER(c + 1, 1, 0, true);
    ITER(c + 2, 2, 1, true);
  }
  ITER(NT - 2, 0, 2, false);  // NT%3==2 -> bufs 0,1
  ITER(NT - 1, 1, 0, false);

  // epilogue: C/D col=idx, row=4g+j within each 16x16 frag
  if constexpr (SCORE) {
    short* S = (short*)Cout;
#pragma unroll
    for (int mf = 0; mf < 2 * MH2; ++mf) {
#pragma unroll
      for (int j = 0; j < 4; ++j) {
        const int row = row0 + wm * RW + (mf % MH2) * 16 + (mf / MH2) * 128 + g * 4 + j;
        float ss = 0.f;
#pragma unroll
        for (int nf = 0; nf < 4; ++nf) {
          const float v = acc[mf][nf][j];
          ss += v * v;
          const int col = col0 + ((BN == 256)
                                      ? (wn * 32 + (nf & 1) * 16 + (nf >> 1) * 128)
                                      : (wn * 64 + nf * 16)) + idx;
          S[(size_t)row * N + col] = f2bf(v);
        }
        ss += __shfl_xor(ss, 1);
        ss += __shfl_xor(ss, 2);
        ss += __shfl_xor(ss, 4);
        ss += __shfl_xor(ss, 8);
        if (idx == 0) atomicAdd(&rowss[row], ss);
      }
    }
  } else {
    float* C = (float*)Cout;
#pragma unroll
    for (int mf = 0; mf < 2 * MH2; ++mf)
#pragma unroll
      for (int j = 0; j < 4; ++j) {
        const int row = row0 + wm * RW + (mf % MH2) * 16 + (mf / MH2) * 128 + g * 4 + j;
#pragma unroll
        for (int nf = 0; nf < 4; ++nf) {
          const int col = col0 + ((BN == 256)
                                      ? (wn * 32 + (nf & 1) * 16 + (nf >> 1) * 128)
                                      : (wn * 64 + nf * 16)) + idx;
          C[(size_t)row * N + col] = acc[mf][nf][j];
        }
      }
  }
}

// ---------------- normalize + exact GELU ----------------
__global__ void norm_gelu_kernel(short* __restrict__ S,
                                 const float* __restrict__ rowss, int total8) {
  int i = blockIdx.x * blockDim.x + threadIdx.x;
  if (i >= total8) return;
  size_t base = (size_t)i * 8;
  int row = (int)(base >> 12);
  float scale = 64.0f * rsqrtf(rowss[row]);
  short8 v = *(short8*)(S + base);
  short8 o;
#pragma unroll
  for (int k = 0; k < 8; ++k) {
    float x = bf2f(v[k]) * scale;
    float gl = 0.5f * x * (1.0f + erff(x * 0.70710678118654752f));
    o[k] = f2bf(gl);
  }
  *(short8*)(S + base) = o;
}

extern "C" void kernel_launch(void* const* d_in, const int* in_sizes, int n_in,
                              void* d_out, int out_size, void* d_ws,
                              size_t ws_size, hipStream_t stream) {
  const float* X = (const float*)d_in[0];
  const float* Kp = (const float*)d_in[1];
  const float* Vp = (const float*)d_in[2];
  float* out = (float*)d_out;

  const int M = 8192, D1 = 1024, Nn = 4096, D2 = 1024;

  char* ws = (char*)d_ws;
  short* Xb = (short*)ws; ws += (size_t)M * D1 * 2;
  short* Kb = (short*)ws; ws += (size_t)Nn * D1 * 2;
  short* Vt = (short*)ws; ws += (size_t)D2 * Nn * 2;
  short* S  = (short*)ws; ws += (size_t)M * Nn * 2;
  float* rowss = (float*)ws;
  (void)ws_size;

  hipMemsetAsync(rowss, 0, M * sizeof(float), stream);
  const int n8x = M * D1 / 8, n8k = Nn * D1 / 8;
  cvt2_kernel<<<(n8x + n8k + 255) / 256, 256, 0, stream>>>(X, Kp, Xb, Kb, n8x, n8x + n8k);
  transpose_bf16_kernel<<<dim3(Nn / 64, D2 / 64), 256, 0, stream>>>(Vp, Vt, Nn, D2);

  // GEMM1: scores (bf16) + row sum-of-squares
  gemm_ring<4096, 1024, 256, 2, 4, true><<<512, 512, 0, stream>>>(Xb, Kb, S, rowss);
  norm_gelu_kernel<<<(M * Nn / 8 + 255) / 256, 256, 0, stream>>>(S, rowss, M * Nn / 8);
  // GEMM2: out (f32)
  gemm_ring<1024, 4096, 128, 4, 2, false><<<256, 512, 0, stream>>>(S, Vt, out, nullptr);
}

// Round 7
// 199.011 us; speedup vs baseline: 1.0462x; 1.0462x over previous
//
#include <hip/hip_runtime.h>
#include <hip/hip_bf16.h>
#include <math.h>
#include <stdint.h>

typedef __attribute__((ext_vector_type(8))) short short8;
typedef __attribute__((ext_vector_type(4))) float f32x4;

__device__ inline short f2bf(float x) {
  union { float f; uint32_t u; } c; c.f = x;
  uint32_t r = (c.u + 0x7FFFu + ((c.u >> 16) & 1u)) >> 16;
  return (short)(uint16_t)r;
}
__device__ inline float bf2f(short s) {
  union { uint32_t u; float f; } c; c.u = ((uint32_t)(uint16_t)s) << 16;
  return c.f;
}

__device__ inline void gload16(const short* src, const char* ldsdst) {
  __builtin_amdgcn_global_load_lds(
      (const __attribute__((address_space(1))) void*)src,
      (__attribute__((address_space(3))) void*)ldsdst, 16, 0, 0);
}

#define BAR __builtin_amdgcn_s_barrier()
#define VMCL(n) asm volatile("s_waitcnt vmcnt(" #n ")" ::: "memory")

// ---------------- prep: f32 -> bf16 for X and Kp in one launch ----------------
__global__ void cvt2_kernel(const float* __restrict__ X, const float* __restrict__ Kp,
                            short* __restrict__ Xb, short* __restrict__ Kb,
                            int n8x, int n8tot) {
  int i = blockIdx.x * blockDim.x + threadIdx.x;
  if (i >= n8tot) return;
  const float* src = (i < n8x) ? X + (size_t)i * 8 : Kp + (size_t)(i - n8x) * 8;
  short* dst = (i < n8x) ? Xb + (size_t)i * 8 : Kb + (size_t)(i - n8x) * 8;
  const float4* p = (const float4*)src;
  float4 a = p[0], b = p[1];
  short8 o;
  o[0] = f2bf(a.x); o[1] = f2bf(a.y); o[2] = f2bf(a.z); o[3] = f2bf(a.w);
  o[4] = f2bf(b.x); o[5] = f2bf(b.y); o[6] = f2bf(b.z); o[7] = f2bf(b.w);
  *(short8*)dst = o;
}

// ---------------- prep: V[4096,1024] f32 -> Vt[1024,4096] bf16 ----------------
__global__ void transpose_bf16_kernel(const float* __restrict__ V,
                                      short* __restrict__ Vt,
                                      int rows, int cols) {
  __shared__ float tile[64][65];
  int n0 = blockIdx.x * 64;
  int d0 = blockIdx.y * 64;
  int t = threadIdx.x;
#pragma unroll
  for (int r = 0; r < 16; ++r) {
    int idx = t + 256 * r;
    int rr = idx >> 6, cc = idx & 63;
    tile[rr][cc] = V[(size_t)(n0 + rr) * cols + d0 + cc];
  }
  __syncthreads();
#pragma unroll
  for (int r = 0; r < 16; ++r) {
    int idx = t + 256 * r;
    int dd = idx >> 6, nn = idx & 63;
    Vt[(size_t)(d0 + dd) * rows + n0 + nn] = f2bf(tile[nn][dd]);
  }
}

// ======== overlap GEMM: C[8192,N] = A[8192,K] x B[N,K]^T ========
// BM=256, BK=32, 8 waves (WM x WN), 3-buffer LDS ring, A-frag reg dbuf.
// Per tile: {LDB; stage(t+2); MFMA mh0; VMC(LQ); BAR; LDA(t+1) || MFMA mh1}.
// Tile t+1's ds_reads overlap tile t's MFMA (no lgkm dep) -> both pipes busy.
template <int N, int K, int BN, int WM, int WN, bool SCORE>
__global__ __launch_bounds__(512, 2) void gemm_ol(
    const short* __restrict__ A, const short* __restrict__ Bm,
    void* __restrict__ Cout, float* __restrict__ rowss) {
  constexpr int NT = K / 32;
  static_assert((NT - 2) % 6 == 0, "tail assumes NT%6==2");
  constexpr int ASZ = 256 * 32 * 2;  // 16 KiB
  constexpr int BSZ = BN * 32 * 2;   // 16 or 8 KiB
  constexpr int SLOT = ASZ + BSZ;
  constexpr int BR = BN / 128;       // B load rounds (2 or 1)
  constexpr int MH2 = 128 / WM / 16; // m-frags per wave per 128-row half
  constexpr int RW = 128 / WM;       // rows per wave within a half
  constexpr int NTN = N / BN;

  __shared__ char lds[3 * SLOT];

  const int t = threadIdx.x, lane = t & 63, w = t >> 6;
  const int wm = w / WN, wn = w % WN;
  const int idx = lane & 15, g = lane >> 4;

  const int bid = blockIdx.x;
  const int id2 = (bid & 7) * (4 * NTN) + (bid >> 3);  // bijective, grid%8==0
  const int row0 = (id2 / NTN) * 256, col0 = (id2 % NTN) * BN;

  // staging: thread t writes LDS byte t*16 of a round; it must carry logical
  // k-slot (t&3) ^ ((row>>1)&3), row = t>>2  ->  source k element offset:
  const int sxor = ((t & 3) ^ ((t >> 3) & 3)) * 8;
  const short* gAp = A + (size_t)(row0 + (t >> 2)) * K + sxor;
  const short* gBp = Bm + (size_t)(col0 + (t >> 2)) * K + sxor;

  auto STG = [&](int s, int T) {
    const int kt = T * 32;
    char* base = (char*)lds + s * SLOT + t * 16;
#pragma unroll
    for (int r = 0; r < 2; ++r)
      gload16(gAp + (size_t)(r * 128) * K + kt, base + r * 8192);
#pragma unroll
    for (int r = 0; r < BR; ++r)
      gload16(gBp + (size_t)(r * 128) * K + kt, base + ASZ + r * 8192);
  };

  // read swizzle: logical k-slot g of row r lives at slot g ^ ((r>>1)&3);
  // row's bits 1-2 equal idx's bits 1-2 (frag bases are multiples of 16).
  const int rdx = (g ^ ((idx >> 1) & 3)) << 4;

  short8 a0[2 * MH2], a1[2 * MH2], bfr[4];
  f32x4 acc[2 * MH2][4] = {};

#define LDA_(S, ARR)                                                     \
  {                                                                      \
    const char* base_ = (char*)lds + (S)*SLOT;                           \
    _Pragma("unroll") for (int mh = 0; mh < 2; ++mh)                     \
        _Pragma("unroll") for (int f = 0; f < MH2; ++f) {                \
      const int row_ = mh * 128 + wm * RW + f * 16 + idx;                \
      ARR[mh * MH2 + f] = *(const short8*)(base_ + row_ * 64 + rdx);     \
    }                                                                    \
  }
#define LDB_(S)                                                          \
  {                                                                      \
    const char* base_ = (char*)lds + (S)*SLOT + ASZ;                     \
    _Pragma("unroll") for (int nf = 0; nf < 4; ++nf) {                   \
      const int col_ = (BN == 256)                                       \
                           ? (wn * 32 + (nf & 1) * 16 + (nf >> 1) * 128) \
                           : (wn * 64 + nf * 16);                        \
      bfr[nf] = *(const short8*)(base_ + (col_ + idx) * 64 + rdx);       \
    }                                                                    \
  }
#define HALF_(MH, ARR)                                                   \
  {                                                                      \
    __builtin_amdgcn_s_setprio(1);                                       \
    _Pragma("unroll") for (int f = 0; f < MH2; ++f)                      \
        _Pragma("unroll") for (int nf = 0; nf < 4; ++nf)                 \
            acc[(MH)*MH2 + f][nf] = __builtin_amdgcn_mfma_f32_16x16x32_bf16( \
                ARR[(MH)*MH2 + f], bfr[nf], acc[(MH)*MH2 + f][nf], 0, 0, 0); \
    __builtin_amdgcn_s_setprio(0);                                       \
  }
#define VMC_LQ                                  \
  do {                                          \
    if constexpr (BR == 2) { VMCL(4); } else { VMCL(3); } \
  } while (0)
#define ITER_(T, CUR, NXT, S, S1, S2) \
  {                                   \
    LDB_(S);                          \
    STG(S2, (T) + 2);                 \
    HALF_(0, CUR);                    \
    VMC_LQ;                           \
    BAR;                              \
    LDA_(S1, NXT);                    \
    HALF_(1, CUR);                    \
  }

  // prologue: stage tiles 0,1; certify 0 (1 stays in flight); preload A(0)
  STG(0, 0);
  STG(1, 1);
  VMC_LQ;
  BAR;
  LDA_(0, a0);

  for (int c = 0; c < NT - 2; c += 6) {
    ITER_(c + 0, a0, a1, 0, 1, 2);
    ITER_(c + 1, a1, a0, 1, 2, 0);
    ITER_(c + 2, a0, a1, 2, 0, 1);
    ITER_(c + 3, a1, a0, 0, 1, 2);
    ITER_(c + 4, a0, a1, 1, 2, 0);
    ITER_(c + 5, a1, a0, 2, 0, 1);
  }
  // tail: tiles NT-2 (parity even, buf 0) and NT-1 (buf 1)
  {
    LDB_(0);
    HALF_(0, a0);
    VMCL(0);  // only tile NT-1's loads outstanding
    BAR;
    LDA_(1, a1);
    HALF_(1, a0);
    LDB_(1);
    HALF_(0, a1);
    HALF_(1, a1);
  }
#undef LDA_
#undef LDB_
#undef HALF_
#undef VMC_LQ
#undef ITER_

  // epilogue: C/D col=idx, row=4g+j within each 16x16 frag (verified R6)
  if constexpr (SCORE) {
    short* S = (short*)Cout;
#pragma unroll
    for (int mf = 0; mf < 2 * MH2; ++mf) {
#pragma unroll
      for (int j = 0; j < 4; ++j) {
        const int row = row0 + wm * RW + (mf % MH2) * 16 + (mf / MH2) * 128 + g * 4 + j;
        float ss = 0.f;
#pragma unroll
        for (int nf = 0; nf < 4; ++nf) {
          const float v = acc[mf][nf][j];
          ss += v * v;
          const int col = col0 + ((BN == 256)
                                      ? (wn * 32 + (nf & 1) * 16 + (nf >> 1) * 128)
                                      : (wn * 64 + nf * 16)) + idx;
          S[(size_t)row * N + col] = f2bf(v);
        }
        ss += __shfl_xor(ss, 1);
        ss += __shfl_xor(ss, 2);
        ss += __shfl_xor(ss, 4);
        ss += __shfl_xor(ss, 8);
        if (idx == 0) atomicAdd(&rowss[row], ss);
      }
    }
  } else {
    float* C = (float*)Cout;
#pragma unroll
    for (int mf = 0; mf < 2 * MH2; ++mf)
#pragma unroll
      for (int j = 0; j < 4; ++j) {
        const int row = row0 + wm * RW + (mf % MH2) * 16 + (mf / MH2) * 128 + g * 4 + j;
#pragma unroll
        for (int nf = 0; nf < 4; ++nf) {
          const int col = col0 + ((BN == 256)
                                      ? (wn * 32 + (nf & 1) * 16 + (nf >> 1) * 128)
                                      : (wn * 64 + nf * 16)) + idx;
          C[(size_t)row * N + col] = acc[mf][nf][j];
        }
      }
  }
}

// ---------------- normalize + exact GELU ----------------
__global__ void norm_gelu_kernel(short* __restrict__ S,
                                 const float* __restrict__ rowss, int total8) {
  int i = blockIdx.x * blockDim.x + threadIdx.x;
  if (i >= total8) return;
  size_t base = (size_t)i * 8;
  int row = (int)(base >> 12);
  float scale = 64.0f * rsqrtf(rowss[row]);
  short8 v = *(short8*)(S + base);
  short8 o;
#pragma unroll
  for (int k = 0; k < 8; ++k) {
    float x = bf2f(v[k]) * scale;
    float gl = 0.5f * x * (1.0f + erff(x * 0.70710678118654752f));
    o[k] = f2bf(gl);
  }
  *(short8*)(S + base) = o;
}

extern "C" void kernel_launch(void* const* d_in, const int* in_sizes, int n_in,
                              void* d_out, int out_size, void* d_ws,
                              size_t ws_size, hipStream_t stream) {
  const float* X = (const float*)d_in[0];
  const float* Kp = (const float*)d_in[1];
  const float* Vp = (const float*)d_in[2];
  float* out = (float*)d_out;

  const int M = 8192, D1 = 1024, Nn = 4096, D2 = 1024;

  char* ws = (char*)d_ws;
  short* Xb = (short*)ws; ws += (size_t)M * D1 * 2;
  short* Kb = (short*)ws; ws += (size_t)Nn * D1 * 2;
  short* Vt = (short*)ws; ws += (size_t)D2 * Nn * 2;
  short* S  = (short*)ws; ws += (size_t)M * Nn * 2;
  float* rowss = (float*)ws;
  (void)ws_size;

  hipMemsetAsync(rowss, 0, M * sizeof(float), stream);
  const int n8x = M * D1 / 8, n8k = Nn * D1 / 8;
  cvt2_kernel<<<(n8x + n8k + 255) / 256, 256, 0, stream>>>(X, Kp, Xb, Kb, n8x, n8x + n8k);
  transpose_bf16_kernel<<<dim3(Nn / 64, D2 / 64), 256, 0, stream>>>(Vp, Vt, Nn, D2);

  // GEMM1: scores (bf16) + row sum-of-squares
  gemm_ol<4096, 1024, 256, 2, 4, true><<<512, 512, 0, stream>>>(Xb, Kb, S, rowss);
  norm_gelu_kernel<<<(M * Nn / 8 + 255) / 256, 256, 0, stream>>>(S, rowss, M * Nn / 8);
  // GEMM2: out (f32)
  gemm_ol<1024, 4096, 128, 4, 2, false><<<256, 512, 0, stream>>>(S, Vt, out, nullptr);
}